// Round 3
// baseline (518.956 us; speedup 1.0000x reference)
//
#include <hip/hip_runtime.h>

typedef __bf16 bf16;
typedef __bf16 bf16x8 __attribute__((ext_vector_type(8)));
typedef float f32x4 __attribute__((ext_vector_type(4)));
typedef int i32x4 __attribute__((ext_vector_type(4)));
typedef signed char i8;

#define T_ 4
#define B_ 8
#define C_ 512
#define D_ 768
#define H_ 8
#define HL_ 2
#define HD_ 96
#define MKV_ 192
#define M2_ 4096            // B*C
#define BCD_ 3145728        // B*C*D
#define M3_ 16384           // T*B*C
#define NCOMB 1152          // q(768) + k(192) + v(192)
#define SUSP_CAP 65536
#define SUSP_WIN 2.2e-3f    // widened for 2-level i8 quant (residual rms ~2e-4, 7+ sigma)

// async global->LDS, 16B per lane (dest = wave-uniform base + lane*16; no pad)
__device__ __forceinline__ void gld16(const void* g, void* l) {
    __builtin_amdgcn_global_load_lds(
        (const __attribute__((address_space(1))) unsigned int*)g,
        (__attribute__((address_space(3))) unsigned int*)l, 16, 0, 0);
}

// ---------------------------------------------------------------------------
// Kernel 1a: prep_scan — xs=lif(x) fp64 scan -> i8 spikes {0,1}; susp reset;
// wmax = max|w| over q/k/v weights via wave-reduce + atomicMax (wmaxb
// memset to 0 on stream before this launch).
// ---------------------------------------------------------------------------
__global__ __launch_bounds__(256) void prep_scan_kernel(
    const float* __restrict__ x, const float* __restrict__ q_w,
    const float* __restrict__ k_w, const float* __restrict__ v_w,
    i8* __restrict__ xs, unsigned* __restrict__ wmaxb,
    unsigned* __restrict__ susp)
{
    const int t0 = blockIdx.x * 256 + threadIdx.x;
    const int stride = gridDim.x * 256;
    if (t0 == 0) susp[0] = 0;
    for (int i = t0; i < BCD_; i += stride) {
        double v = 0.0;
        #pragma unroll
        for (int t = 0; t < T_; ++t) {
            v = v * 0.5 + (double)x[(size_t)t * BCD_ + i];
            i8 s = (v >= 1.0) ? (i8)1 : (i8)0;
            xs[(size_t)t * BCD_ + i] = s;
            if (s) v = 0.0;
        }
    }
    float m = 0.f;
    for (int i = t0; i < NCOMB * D_; i += stride) {
        int row = i / D_, col = i - row * D_;
        float v;
        if (row < 768)      v = q_w[(size_t)row * D_ + col];
        else if (row < 960) v = k_w[(size_t)(row - 768) * D_ + col];
        else                v = v_w[(size_t)(row - 960) * D_ + col];
        m = fmaxf(m, fabsf(v));
    }
    #pragma unroll
    for (int off = 1; off < 64; off <<= 1)
        m = fmaxf(m, __shfl_xor(m, off));
    if ((threadIdx.x & 63) == 0)
        atomicMax(wmaxb, __float_as_uint(m));   // nonneg floats: bit-monotone
}

// ---------------------------------------------------------------------------
// Kernel 1b: prep_quant — two-level i8 quantization of q/k/v weights
// (w ~= s1*h1 + s2*h2, s1 = wmax/127, s2 = s1/127), wo bf16 cvt.
// ---------------------------------------------------------------------------
__global__ __launch_bounds__(256) void prep_quant_kernel(
    const float* __restrict__ q_w, const float* __restrict__ k_w,
    const float* __restrict__ v_w, const float* __restrict__ wo_w,
    const unsigned* __restrict__ wmaxb,
    i8* __restrict__ w1, i8* __restrict__ w2, bf16* __restrict__ wo_bf)
{
    const float wmax = __uint_as_float(*wmaxb);
    const float s1   = wmax * (1.0f / 127.0f);
    const float s2   = s1 * (1.0f / 127.0f);
    const float i1   = 1.0f / s1;
    const float i2   = 1.0f / s2;
    const int t0 = blockIdx.x * 256 + threadIdx.x;
    const int stride = gridDim.x * 256;
    for (int i = t0; i < NCOMB * D_; i += stride) {
        int row = i / D_, col = i - row * D_;
        float v;
        if (row < 768)      v = q_w[(size_t)row * D_ + col];
        else if (row < 960) v = k_w[(size_t)(row - 768) * D_ + col];
        else                v = v_w[(size_t)(row - 960) * D_ + col];
        float h1 = rintf(v * i1);                // |h1| <= 127
        float r  = fmaf(-s1, h1, v);             // |r| <= s1/2
        float h2 = rintf(r * i2);                // |h2| <= 64
        w1[i] = (i8)(int)h1;
        w2[i] = (i8)(int)h2;
    }
    for (int i = t0; i < D_ * D_; i += stride)
        wo_bf[i] = (bf16)wo_w[i];
}

// ---------------------------------------------------------------------------
// Kernel 2: combined spiking projection, i8 path. Block 64(m)x64(n), BK=64
// i8 elems (=64 BYTES, byte-identical staging geometry to the verified bf16
// BK=32 kernel). Per K-step: 2 i8 MFMAs (16x16x64) per (t,mi,ni) into ONE
// i32 acc via y/s2 = Sum(127a)*h1 + Sum(a)*h2; 127a = (a<<7)-a in VALU
// (bytes are {0,1}: no cross-byte carries). 12 K-steps (halved), same T4
// counted-vmcnt full-iteration prefetch, same 4-slot XOR swizzle, same
// XCD-aware block swizzle. LIF scan epilogue; suspects -> list.
// ---------------------------------------------------------------------------
__global__ __launch_bounds__(256, 3) void proj_lif_kernel(
    const i8* __restrict__ xs, const i8* __restrict__ W1,
    const i8* __restrict__ W2, const unsigned* __restrict__ wmaxb,
    bf16* __restrict__ q_sp, bf16* __restrict__ k_sp, bf16* __restrict__ v_sp,
    unsigned* __restrict__ susp)
{
    __shared__ __align__(16) i8 A0[T_][64 * 64];   // 16 KB
    __shared__ __align__(16) i8 A1[T_][64 * 64];   // 16 KB
    __shared__ __align__(16) i8 G0[64 * 64];       //  4 KB (h1)
    __shared__ __align__(16) i8 G1[64 * 64];       //  4 KB
    __shared__ __align__(16) i8 E0[64 * 64];       //  4 KB (h2)
    __shared__ __align__(16) i8 E1[64 * 64];       //  4 KB  (48 KB total)

    const int tid  = threadIdx.x;
    const int wave = tid >> 6, lane = tid & 63;
    const int m16  = lane & 15, quad = lane >> 4;
    const int wm   = wave >> 1, wn = wave & 1;

    // bijective XCD swizzle: xcd = bid&7 gets m-tiles [xcd*8, xcd*8+8) x all n
    const int bid   = blockIdx.y * 64 + blockIdx.x;   // grid (64, 18)
    const int xcd   = bid & 7;
    const int local = bid >> 3;                        // 0..143
    const int m0    = ((xcd << 3) | (local & 7)) * 64; // over M2
    const int n0    = (local >> 3) * 64;               // over NCOMB

    // output section for this wave's 32 columns
    const int colb = n0 + wn * 32;
    bf16* outp; int Nloc, cb;
    if (colb < 768)      { outp = q_sp; Nloc = 768; cb = colb; }
    else if (colb < 960) { outp = k_sp; Nloc = 192; cb = colb - 768; }
    else                 { outp = v_sp; Nloc = 192; cb = colb - 960; }

    const float s2 = __uint_as_float(*wmaxb) * (1.0f / (127.0f * 127.0f));

    i32x4 acc[T_][2][2];
    #pragma unroll
    for (int t = 0; t < T_; t++)
        #pragma unroll
        for (int a = 0; a < 2; a++)
            #pragma unroll
            for (int b = 0; b < 2; b++) { i32x4 z = {0,0,0,0}; acc[t][a][b] = z; }

    // staging geometry (bytes): chunk = tid -> row = tid>>2, slot = tid&3,
    // source seg = slot ^ ((row>>1)&3)  (inverse swizzle on global src)
    const int srow = tid >> 2;
    const int sseg = (tid & 3) ^ ((tid >> 3) & 3);

#define STAGE(Ab, Gb, Eb, k0) do {                                            \
    _Pragma("unroll")                                                         \
    for (int t = 0; t < T_; t++)                                              \
        gld16(xs + (size_t)(t * M2_ + m0 + srow) * D_ + (k0) + sseg * 16,     \
              &Ab[t][tid * 16]);                                              \
    gld16(W1 + (size_t)(n0 + srow) * D_ + (k0) + sseg * 16, &Gb[tid * 16]);   \
    gld16(W2 + (size_t)(n0 + srow) * D_ + (k0) + sseg * 16, &Eb[tid * 16]);   \
} while (0)

    i32x4 a[T_][2], b1[2], b2[2];

#define LOADREGS(Ab, Gb, Eb) do {                                             \
    _Pragma("unroll")                                                         \
    for (int mi = 0; mi < 2; mi++) {                                          \
        int row = wm * 32 + mi * 16 + m16;                                    \
        int off = row * 64 + ((quad ^ ((row >> 1) & 3)) * 16);                \
        _Pragma("unroll")                                                     \
        for (int t = 0; t < T_; t++) a[t][mi] = *(const i32x4*)&Ab[t][off];   \
    }                                                                         \
    _Pragma("unroll")                                                         \
    for (int ni = 0; ni < 2; ni++) {                                          \
        int row = wn * 32 + ni * 16 + m16;                                    \
        int off = row * 64 + ((quad ^ ((row >> 1) & 3)) * 16);                \
        b1[ni] = *(const i32x4*)&Gb[off];                                     \
        b2[ni] = *(const i32x4*)&Eb[off];                                     \
    }                                                                         \
} while (0)

#define DOMFMA() do {                                                         \
    __builtin_amdgcn_s_setprio(1);                                            \
    _Pragma("unroll")                                                         \
    for (int t = 0; t < T_; t++)                                              \
        _Pragma("unroll")                                                     \
        for (int mi = 0; mi < 2; mi++) {                                      \
            i32x4 a127 = (a[t][mi] << 7) - a[t][mi];                          \
            _Pragma("unroll")                                                 \
            for (int ni = 0; ni < 2; ni++) {                                  \
                acc[t][mi][ni] = __builtin_amdgcn_mfma_i32_16x16x64_i8(       \
                    a127, b1[ni], acc[t][mi][ni], 0, 0, 0);                   \
                acc[t][mi][ni] = __builtin_amdgcn_mfma_i32_16x16x64_i8(       \
                    a[t][mi], b2[ni], acc[t][mi][ni], 0, 0, 0);               \
            }                                                                 \
        }                                                                     \
    __builtin_amdgcn_s_setprio(0);                                            \
} while (0)

// all waves finished reading the buffer we are about to overwrite
#define READS_DONE() do {                                                     \
    asm volatile("s_waitcnt lgkmcnt(0)" ::: "memory");                        \
    __builtin_amdgcn_s_barrier();                                             \
    __builtin_amdgcn_sched_barrier(0);                                        \
} while (0)

// counted wait: next buffer's 6 loads (issued a full iter ago) landed;
// the 6 just-issued stay in flight
#define NEXT_READY(N) do {                                                    \
    asm volatile("s_waitcnt vmcnt(" #N ")" ::: "memory");                     \
    __builtin_amdgcn_s_barrier();                                             \
} while (0)

    STAGE(A0, G0, E0, 0);
    STAGE(A1, G1, E1, 64);
    NEXT_READY(6);                       // buf0 ready, buf1 in flight

    for (int s = 0; s < 10; s += 2) {    // iters u = s (buf0), u = s+1 (buf1)
        LOADREGS(A0, G0, E0);
        READS_DONE();
        STAGE(A0, G0, E0, (s + 2) * 64);
        DOMFMA();
        NEXT_READY(6);                   // buf1 (tile s+1) ready

        LOADREGS(A1, G1, E1);
        READS_DONE();
        STAGE(A1, G1, E1, (s + 3) * 64);
        DOMFMA();
        NEXT_READY(6);                   // buf0 (tile s+2) ready
    }
    // iter 10 (buf0): no more staging
    LOADREGS(A0, G0, E0);
    READS_DONE();
    DOMFMA();
    NEXT_READY(0);                       // buf1 (tile 11) ready
    // iter 11 (buf1)
    LOADREGS(A1, G1, E1);
    DOMFMA();

#undef STAGE
#undef LOADREGS
#undef DOMFMA
#undef READS_DONE
#undef NEXT_READY

    // LIF scan over t (registers only) + spike stores + suspect flags
    #pragma unroll
    for (int mi = 0; mi < 2; mi++)
        #pragma unroll
        for (int ni = 0; ni < 2; ni++)
            #pragma unroll
            for (int rr = 0; rr < 4; rr++) {
                int row = m0 + wm * 32 + mi * 16 + quad * 4 + rr;
                int lc  = cb + ni * 16 + m16;
                float v = 0.f;
                bool suspect = false;
                #pragma unroll
                for (int t = 0; t < T_; t++) {
                    v = v * 0.5f + s2 * (float)acc[t][mi][ni][rr];
                    float d = v - 1.0f;
                    if (fabsf(d) < SUSP_WIN) suspect = true;
                    float sp = (d >= 0.f) ? 1.f : 0.f;
                    v *= (1.f - sp);
                    outp[(size_t)(t * M2_ + row) * Nloc + lc] = (bf16)sp;
                }
                if (suspect) {
                    int ccol = n0 + wn * 32 + ni * 16 + m16;
                    unsigned idx = atomicAdd(susp, 1u);
                    if (idx < SUSP_CAP) susp[1 + idx] = (unsigned)(row * 2048 + ccol);
                }
            }
}

// ---------------------------------------------------------------------------
// Kernel 2b: fp64 fixup of suspect trajectories. One wave per suspect,
// vectorized: float4 weight loads + 4 spike bytes per lane.
// ---------------------------------------------------------------------------
__global__ __launch_bounds__(256) void fixup_kernel(
    const i8* __restrict__ xs, const float* __restrict__ q_w,
    const float* __restrict__ k_w, const float* __restrict__ v_w,
    bf16* __restrict__ q_sp, bf16* __restrict__ k_sp, bf16* __restrict__ v_sp,
    const unsigned* __restrict__ susp)
{
    unsigned count = susp[0];
    if (count > SUSP_CAP) count = SUSP_CAP;
    const int lane = threadIdx.x & 63;
    const int wid  = (blockIdx.x * blockDim.x + threadIdx.x) >> 6;
    const int nw   = (gridDim.x * blockDim.x) >> 6;
    for (unsigned i = wid; i < count; i += nw) {
        unsigned e = susp[1 + i];
        int row = e >> 11, col = e & 2047;
        const float* W; bf16* outp; int Nloc, lc;
        if (col < 768)      { W = q_w + (size_t)col * D_;         outp = q_sp; Nloc = 768; lc = col; }
        else if (col < 960) { W = k_w + (size_t)(col - 768) * D_; outp = k_sp; Nloc = 192; lc = col - 768; }
        else                { W = v_w + (size_t)(col - 960) * D_; outp = v_sp; Nloc = 192; lc = col - 960; }
        double v = 0.0;
        for (int t = 0; t < T_; ++t) {
            const i8* ar = xs + (size_t)(t * M2_ + row) * D_;
            double y = 0.0;
            for (int k = lane * 4; k < D_; k += 256) {
                f32x4 wv = *(const f32x4*)(W + k);
                unsigned ab = *(const unsigned*)(ar + k);
                if (ab & 0x000000ffu) y += (double)wv[0];
                if (ab & 0x0000ff00u) y += (double)wv[1];
                if (ab & 0x00ff0000u) y += (double)wv[2];
                if (ab & 0xff000000u) y += (double)wv[3];
            }
            #pragma unroll
            for (int off = 1; off < 64; off <<= 1)
                y += __shfl_xor(y, off);
            v = v * 0.5 + y;
            unsigned sp = (v >= 1.0) ? 1u : 0u;
            if (lane == 0) outp[(size_t)(t * M2_ + row) * Nloc + lc] = (bf16)(float)sp;
            if (sp) v = 0.0;
        }
    }
}

// ---------------------------------------------------------------------------
// Kernel 3: partial k^T v. Block (g, cc): c-range cc*64..+64 (8 slices ->
// 512 blocks, 2/CU). Vectorized bf16x8 global loads, scalar LDS transpose
// scatter. fp32 exact integer partials -> M_part[cc][g][96][96].
// ---------------------------------------------------------------------------
__global__ __launch_bounds__(256) void ktv_kernel(
    const bf16* __restrict__ k_sp, const bf16* __restrict__ v_sp,
    float* __restrict__ M_part)
{
    const int g    = blockIdx.x;
    const int cc   = blockIdx.y;
    const int kvh  = g % HL_;
    const int tb   = g / HL_;
    const int wave = threadIdx.x >> 6;
    const int lane = threadIdx.x & 63;
    const int m16  = lane & 15, quad = lane >> 4;

    __shared__ __align__(16) bf16 klds[96 * 40];
    __shared__ __align__(16) bf16 vlds[96 * 40];

    f32x4 acc[9];
    #pragma unroll
    for (int i = 0; i < 9; i++) { f32x4 z = {0.f,0.f,0.f,0.f}; acc[i] = z; }

    const bf16* kbase = k_sp + ((size_t)tb * C_ + cc * 64) * MKV_ + kvh * HD_;
    const bf16* vbase = v_sp + ((size_t)tb * C_ + cc * 64) * MKV_ + kvh * HD_;

    for (int c0 = 0; c0 < 64; c0 += 32) {
        __syncthreads();
        // 32c x 12segs x 2 arrays = 768 bf16x8 chunks, 3 per thread
        for (int ci = threadIdx.x; ci < 768; ci += 256) {
            int arr = ci & 1;
            int pos = ci >> 1;
            int c = pos / 12, seg = pos - c * 12;
            const bf16* src = (arr ? vbase : kbase) + (size_t)(c0 + c) * MKV_ + seg * 8;
            bf16x8 val = *(const bf16x8*)src;
            bf16* dst = arr ? vlds : klds;
            #pragma unroll
            for (int e = 0; e < 8; e++)
                dst[(seg * 8 + e) * 40 + c] = val[e];
        }
        __syncthreads();
        #pragma unroll
        for (int i = 0; i < 9; i++) {
            int tile = wave + i * 4;
            int mt = tile / 6, nt = tile % 6;
            bf16x8 a = *(const bf16x8*)(&klds[(mt * 16 + m16) * 40 + quad * 8]);
            bf16x8 b = *(const bf16x8*)(&vlds[(nt * 16 + m16) * 40 + quad * 8]);
            acc[i] = __builtin_amdgcn_mfma_f32_16x16x32_bf16(a, b, acc[i], 0, 0, 0);
        }
    }
    float* op = M_part + ((size_t)cc * 64 + g) * HD_ * HD_;
    #pragma unroll
    for (int i = 0; i < 9; i++) {
        int tile = wave + i * 4;
        int mt = tile / 6, nt = tile % 6;
        #pragma unroll
        for (int r = 0; r < 4; r++) {
            int d = mt * 16 + quad * 4 + r;
            int j = nt * 16 + m16;
            op[(size_t)j * HD_ + d] = acc[i][r];
        }
    }
}

// ---------------------------------------------------------------------------
// Kernel 3b: sum 8 partials, split to exact hi/lo bf16.
// ---------------------------------------------------------------------------
__global__ __launch_bounds__(256) void cvtM_kernel(
    const float* __restrict__ M_part, bf16* __restrict__ M_hi,
    bf16* __restrict__ M_lo)
{
    int i = blockIdx.x * 256 + threadIdx.x;
    if (i >= 64 * HD_ * HD_) return;
    float m = 0.f;
    #pragma unroll
    for (int j = 0; j < 8; j++)
        m += M_part[i + (size_t)j * 589824];
    bf16 h = (bf16)m;
    M_hi[i] = h;
    M_lo[i] = (bf16)(m - (float)h);
}

// ---------------------------------------------------------------------------
// Kernel 4: out_attn = 0.1 * q @ M. Block (tbh, c128): M hi/lo staged once
// in padded LDS (row stride 104 elems -> conflict-free b128 reads).
// ---------------------------------------------------------------------------
__global__ __launch_bounds__(256) void qm_kernel(
    const bf16* __restrict__ q_sp, const bf16* __restrict__ M_hi,
    const bf16* __restrict__ M_lo, bf16* __restrict__ out_attn)
{
    const int tbh  = blockIdx.x;
    const int h    = tbh % H_;
    const int tb   = tbh / H_;
    const int g    = tb * HL_ + (h >> 2);
    const int wave = threadIdx.x >> 6;
    const int lane = threadIdx.x & 63;
    const int m16  = lane & 15, quad = lane >> 4;
    const int cw   = blockIdx.y * 128 + wave * 32;

    __shared__ __align__(16) bf16 Mh[96 * 104];
    __shared__ __align__(16) bf16 Ml[96 * 104];
    {   // stage M: 96 rows x 12 segs = 1152 chunks per array
        const bf16* gh = M_hi + (size_t)g * HD_ * HD_;
        const bf16* gl = M_lo + (size_t)g * HD_ * HD_;
        #pragma unroll
        for (int j = 0; j < 5; j++) {
            int ci = j * 256 + threadIdx.x;
            if (ci < 1152) {
                int row = ci / 12, seg = ci % 12;
                *(bf16x8*)&Mh[row * 104 + seg * 8] = *(const bf16x8*)(gh + row * HD_ + seg * 8);
                *(bf16x8*)&Ml[row * 104 + seg * 8] = *(const bf16x8*)(gl + row * HD_ + seg * 8);
            }
        }
    }
    __syncthreads();

    f32x4 acc[2][6];
    #pragma unroll
    for (int mi = 0; mi < 2; mi++)
        #pragma unroll
        for (int nt = 0; nt < 6; nt++) { f32x4 z = {0.f,0.f,0.f,0.f}; acc[mi][nt] = z; }

    #pragma unroll
    for (int ks = 0; ks < 3; ++ks) {
        bf16x8 a[2];
        #pragma unroll
        for (int mi = 0; mi < 2; mi++)
            a[mi] = *(const bf16x8*)(q_sp + ((size_t)(tb * C_ + cw + mi * 16 + m16)) * D_
                                     + h * HD_ + ks * 32 + quad * 8);
        #pragma unroll
        for (int nt = 0; nt < 6; ++nt) {
            bf16x8 bh = *(const bf16x8*)&Mh[(nt * 16 + m16) * 104 + ks * 32 + quad * 8];
            bf16x8 bl = *(const bf16x8*)&Ml[(nt * 16 + m16) * 104 + ks * 32 + quad * 8];
            #pragma unroll
            for (int mi = 0; mi < 2; mi++) {
                acc[mi][nt] = __builtin_amdgcn_mfma_f32_16x16x32_bf16(a[mi], bh, acc[mi][nt], 0, 0, 0);
                acc[mi][nt] = __builtin_amdgcn_mfma_f32_16x16x32_bf16(a[mi], bl, acc[mi][nt], 0, 0, 0);
            }
        }
    }
    #pragma unroll
    for (int mi = 0; mi < 2; mi++)
        #pragma unroll
        for (int nt = 0; nt < 6; nt++)
            #pragma unroll
            for (int r = 0; r < 4; r++) {
                int c = cw + mi * 16 + quad * 4 + r;
                int j = nt * 16 + m16;
                out_attn[((size_t)(tb * C_ + c)) * D_ + h * HD_ + j] = (bf16)(0.1f * acc[mi][nt][r]);
            }
}

// ---------------------------------------------------------------------------
// Kernel 5: final = out_attn @ wo^T. 128x128 tile, BK=64, XOR-swizzled LDS.
// ---------------------------------------------------------------------------
__global__ __launch_bounds__(256) void final_gemm_kernel(
    const bf16* __restrict__ A, const bf16* __restrict__ W, float* __restrict__ out)
{
    __shared__ __align__(16) bf16 Alds[128 * 64];   // 16 KB
    __shared__ __align__(16) bf16 Blds[128 * 64];   // 16 KB
    const int tid  = threadIdx.x;
    const int wave = tid >> 6, lane = tid & 63;
    const int m16  = lane & 15, quad = lane >> 4;
    const int wm   = wave >> 1, wn = wave & 1;
    const int m0   = blockIdx.x * 128, n0 = blockIdx.y * 128;

    f32x4 acc[4][4];
    #pragma unroll
    for (int a = 0; a < 4; a++)
        #pragma unroll
        for (int b = 0; b < 4; b++) { f32x4 z = {0.f,0.f,0.f,0.f}; acc[a][b] = z; }

    for (int k0 = 0; k0 < D_; k0 += 64) {
        __syncthreads();
        #pragma unroll
        for (int j = 0; j < 4; j++) {
            int ci = j * 256 + tid;
            int row = ci >> 3, slot = ci & 7;
            int seg = slot ^ ((row >> 1) & 7);
            gld16(A + (size_t)(m0 + row) * D_ + k0 + seg * 8, Alds + ci * 8);
            gld16(W + (size_t)(n0 + row) * D_ + k0 + seg * 8, Blds + ci * 8);
        }
        __syncthreads();
        #pragma unroll
        for (int kc = 0; kc < 2; kc++) {
            bf16x8 a[4], b[4];
            #pragma unroll
            for (int mi = 0; mi < 4; mi++) {
                int row = wm * 64 + mi * 16 + m16;
                a[mi] = *(const bf16x8*)&Alds[row * 64 + (((kc * 4 + quad) ^ ((row >> 1) & 7)) * 8)];
            }
            #pragma unroll
            for (int ni = 0; ni < 4; ni++) {
                int row = wn * 64 + ni * 16 + m16;
                b[ni] = *(const bf16x8*)&Blds[row * 64 + (((kc * 4 + quad) ^ ((row >> 1) & 7)) * 8)];
            }
            #pragma unroll
            for (int mi = 0; mi < 4; mi++)
                #pragma unroll
                for (int ni = 0; ni < 4; ni++)
                    acc[mi][ni] = __builtin_amdgcn_mfma_f32_16x16x32_bf16(a[mi], b[ni], acc[mi][ni], 0, 0, 0);
        }
    }
    #pragma unroll
    for (int mi = 0; mi < 4; mi++)
        #pragma unroll
        for (int ni = 0; ni < 4; ni++)
            #pragma unroll
            for (int r = 0; r < 4; r++) {
                int row = m0 + wm * 64 + mi * 16 + quad * 4 + r;
                int col = n0 + wn * 64 + ni * 16 + m16;
                out[(size_t)row * D_ + col] = acc[mi][ni][r];
            }
}

// ---------------------------------------------------------------------------
extern "C" void kernel_launch(void* const* d_in, const int* in_sizes, int n_in,
                              void* d_out, int out_size, void* d_ws, size_t ws_size,
                              hipStream_t stream) {
    const float* x    = (const float*)d_in[0];
    const float* q_w  = (const float*)d_in[1];
    const float* k_w  = (const float*)d_in[2];
    const float* v_w  = (const float*)d_in[3];
    const float* wo_w = (const float*)d_in[4];
    float* out = (float*)d_out;

    char* ws = (char*)d_ws;
    i8*   xs    = (i8*)(ws);                    // 12,582,912 used (T,M2,768) i8 (region 25 MB)
    bf16* q_sp  = (bf16*)(ws + 25165824);       // 25,165,824  (T,M2,768)
    bf16* k_sp  = (bf16*)(ws + 50331648);       //  6,291,456  (T,M2,192)
    bf16* v_sp  = (bf16*)(ws + 56623104);       //  6,291,456  (T,M2,192)
    i8*   w1    = (i8*)(ws + 62914560);         //    884,736  (1152,768) i8 level1
    i8*   w2    = (i8*)(ws + 63799296);         //    884,736  i8 level2
    unsigned* wmaxb = (unsigned*)(ws + 64684032); //        4  max|w| bits
    bf16* wo_bf = (bf16*)(ws + 66453504);       //  1,179,648
    bf16* M_hi  = (bf16*)(ws + 67633152);       //  1,179,648  (64,96,96)
    bf16* M_lo  = (bf16*)(ws + 68812800);       //  1,179,648
    unsigned* susp = (unsigned*)(ws + 69992448);//    262,148  (count + entries)
    bf16* out_attn = (bf16*)ws;                 // alias: xs dead after fixup
    float* M_part  = out;                       // d_out as scratch (18.9 MB of 50 MB)

    hipMemsetAsync(wmaxb, 0, 4, stream);
    hipLaunchKernelGGL(prep_scan_kernel, dim3(2048), dim3(256), 0, stream,
                       x, q_w, k_w, v_w, xs, wmaxb, susp);
    hipLaunchKernelGGL(prep_quant_kernel, dim3(512), dim3(256), 0, stream,
                       q_w, k_w, v_w, wo_w, wmaxb, w1, w2, wo_bf);
    hipLaunchKernelGGL(proj_lif_kernel, dim3(M2_ / 64, NCOMB / 64), dim3(256), 0, stream,
                       xs, w1, w2, wmaxb, q_sp, k_sp, v_sp, susp);
    hipLaunchKernelGGL(fixup_kernel, dim3(512), dim3(256), 0, stream,
                       xs, q_w, k_w, v_w, q_sp, k_sp, v_sp, susp);
    hipLaunchKernelGGL(ktv_kernel, dim3(T_ * B_ * HL_, 8), dim3(256), 0, stream,
                       k_sp, v_sp, M_part);
    hipLaunchKernelGGL(cvtM_kernel, dim3((64 * HD_ * HD_ + 255) / 256), dim3(256), 0, stream,
                       M_part, M_hi, M_lo);
    hipLaunchKernelGGL(qm_kernel, dim3(T_ * B_ * H_, C_ / 128), dim3(256), 0, stream,
                       q_sp, M_hi, M_lo, out_attn);
    hipLaunchKernelGGL(final_gemm_kernel, dim3(M3_ / 128, D_ / 128), dim3(256), 0, stream,
                       out_attn, wo_bf, out);
}

// Round 4
// 278.629 us; speedup vs baseline: 1.8625x; 1.8625x over previous
//
#include <hip/hip_runtime.h>

typedef __bf16 bf16;
typedef __bf16 bf16x8 __attribute__((ext_vector_type(8)));
typedef float f32x4 __attribute__((ext_vector_type(4)));

#define T_ 4
#define B_ 8
#define C_ 512
#define D_ 768
#define H_ 8
#define HL_ 2
#define HD_ 96
#define MKV_ 192
#define M2_ 4096            // B*C
#define BCD_ 3145728        // B*C*D
#define M3_ 16384           // T*B*C
#define NCOMB 1152          // q(768) + k(192) + v(192)
#define SUSP_CAP 65536
#define SUSP_WIN 2e-4f

// async global->LDS, 16B per lane (dest = wave-uniform base + lane*16; no pad)
__device__ __forceinline__ void gld16(const bf16* g, bf16* l) {
    __builtin_amdgcn_global_load_lds(
        (const __attribute__((address_space(1))) unsigned int*)g,
        (__attribute__((address_space(3))) unsigned int*)l, 16, 0, 0);
}

// ---------------------------------------------------------------------------
// Kernel 1: fused prep — xs=lif(x) fp64 scan, q/k/v weight hi/lo split,
// wo bf16 cvt, susp counter reset. Grid-stride.  (r2-exact)
// ---------------------------------------------------------------------------
__global__ __launch_bounds__(256) void prep_kernel(
    const float* __restrict__ x, const float* __restrict__ q_w,
    const float* __restrict__ k_w, const float* __restrict__ v_w,
    const float* __restrict__ wo_w, bf16* __restrict__ xs,
    bf16* __restrict__ whi, bf16* __restrict__ wlo, bf16* __restrict__ wo_bf,
    unsigned* __restrict__ susp)
{
    const int t0 = blockIdx.x * 256 + threadIdx.x;
    const int stride = gridDim.x * 256;
    if (t0 == 0) susp[0] = 0;
    for (int i = t0; i < BCD_; i += stride) {
        double v = 0.0;
        #pragma unroll
        for (int t = 0; t < T_; ++t) {
            v = v * 0.5 + (double)x[(size_t)t * BCD_ + i];
            float s = (v >= 1.0) ? 1.0f : 0.0f;
            xs[(size_t)t * BCD_ + i] = (bf16)s;
            if (s != 0.0f) v = 0.0;
        }
    }
    for (int i = t0; i < NCOMB * D_; i += stride) {
        int row = i / D_, col = i - row * D_;
        float v;
        if (row < 768)      v = q_w[(size_t)row * D_ + col];
        else if (row < 960) v = k_w[(size_t)(row - 768) * D_ + col];
        else                v = v_w[(size_t)(row - 960) * D_ + col];
        bf16 h = (bf16)v;
        whi[i] = h;
        wlo[i] = (bf16)(v - (float)h);
    }
    for (int i = t0; i < D_ * D_; i += stride)
        wo_bf[i] = (bf16)wo_w[i];
}

// ---------------------------------------------------------------------------
// Kernel 2: combined spiking projection, A-DIRECT structure.
// Block 64(m)x64(n), BK=32, 4 waves; wave w owns rows [w*16, w*16+16) and
// ALL 64 n-cols: acc[t][ni=4]. A fragments are loaded GLOBAL->VGPR directly
// (per-lane addr == MFMA A-layout; each A byte read once per block; L2-hot
// via XCD swizzle), register-double-buffered one K-step ahead (aP/aN).
// Only B (weights hi/lo, shared by all 4 waves) is LDS-staged, dbuffered,
// with counted vmcnt (r2-proven). LDS traffic per step drops from 12 reads
// +6 DMA to 8 reads+2 DMA per wave -> LDS pipe no longer the limiter.
// sched_barrier pins B-DMA-before-A-load issue order so counted waits are
// exact. XOR swizzle on B (4 slots). LIF scan epilogue; suspects -> list.
// ---------------------------------------------------------------------------
__global__ __launch_bounds__(256, 2) void proj_lif_kernel(
    const bf16* __restrict__ xs, const bf16* __restrict__ Whi,
    const bf16* __restrict__ Wlo,
    bf16* __restrict__ q_sp, bf16* __restrict__ k_sp, bf16* __restrict__ v_sp,
    unsigned* __restrict__ susp)
{
    __shared__ __align__(16) bf16 H0[64 * 32];       //  4 KB (Whi buf0)
    __shared__ __align__(16) bf16 H1[64 * 32];       //  4 KB
    __shared__ __align__(16) bf16 L0[64 * 32];       //  4 KB (Wlo buf0)
    __shared__ __align__(16) bf16 L1[64 * 32];       //  4 KB  (16 KB total)

    const int tid  = threadIdx.x;
    const int wave = tid >> 6, lane = tid & 63;
    const int m16  = lane & 15, quad = lane >> 4;

    // bijective XCD swizzle: xcd = bid&7 gets m-tiles [xcd*8, xcd*8+8) x all n
    const int bid   = blockIdx.y * 64 + blockIdx.x;   // grid (64, 18)
    const int xcd   = bid & 7;
    const int local = bid >> 3;                        // 0..143
    const int m0    = ((xcd << 3) | (local & 7)) * 64; // over M2
    const int n0    = (local >> 3) * 64;               // over NCOMB

    // output section (block-uniform: 64-col tiles never cross q/k/v bounds)
    bf16* outp; int Nloc, cb;
    if (n0 < 768)      { outp = q_sp; Nloc = 768; cb = n0; }
    else if (n0 < 960) { outp = k_sp; Nloc = 192; cb = n0 - 768; }
    else               { outp = v_sp; Nloc = 192; cb = n0 - 960; }

    f32x4 acc[T_][4];
    #pragma unroll
    for (int t = 0; t < T_; t++)
        #pragma unroll
        for (int ni = 0; ni < 4; ni++) { f32x4 z = {0.f,0.f,0.f,0.f}; acc[t][ni] = z; }

    // B staging geometry: 64 rows x 4 slots, 1 chunk/thread per array
    const int srow = tid >> 2;
    const int sseg = (tid & 3) ^ ((tid >> 3) & 3);

    // A fragment base: lane reads xs[t][m0 + wave*16 + m16][k0 + quad*8 ..+8]
    const bf16* abase = xs + (size_t)(m0 + wave * 16 + m16) * D_ + quad * 8;

#define STAGE_B(Hb, Lb, k0) do {                                              \
    gld16(Whi + (size_t)(n0 + srow) * D_ + (k0) + sseg * 8, &Hb[tid * 8]);    \
    gld16(Wlo + (size_t)(n0 + srow) * D_ + (k0) + sseg * 8, &Lb[tid * 8]);    \
} while (0)

    bf16x8 aP[T_], aN[T_], b1[4], b2[4];

#define PREF_A(dst, k0) do {                                                  \
    _Pragma("unroll")                                                         \
    for (int t = 0; t < T_; t++)                                              \
        dst[t] = *(const bf16x8*)(abase + (size_t)t * (size_t)(M2_) * D_ + (k0)); \
} while (0)

#define LOADREGS_B(Hb, Lb) do {                                               \
    _Pragma("unroll")                                                         \
    for (int ni = 0; ni < 4; ni++) {                                          \
        int row = ni * 16 + m16;                                              \
        int off = row * 32 + ((quad ^ ((row >> 1) & 3)) * 8);                 \
        b1[ni] = *(const bf16x8*)&Hb[off];                                    \
        b2[ni] = *(const bf16x8*)&Lb[off];                                    \
    }                                                                         \
} while (0)

#define DOMFMA(av) do {                                                       \
    __builtin_amdgcn_s_setprio(1);                                            \
    _Pragma("unroll")                                                         \
    for (int t = 0; t < T_; t++)                                              \
        _Pragma("unroll")                                                     \
        for (int ni = 0; ni < 4; ni++) {                                      \
            acc[t][ni] = __builtin_amdgcn_mfma_f32_16x16x32_bf16(             \
                av[t], b1[ni], acc[t][ni], 0, 0, 0);                          \
            acc[t][ni] = __builtin_amdgcn_mfma_f32_16x16x32_bf16(             \
                av[t], b2[ni], acc[t][ni], 0, 0, 0);                          \
        }                                                                     \
    __builtin_amdgcn_s_setprio(0);                                            \
} while (0)

// all waves finished reading the LDS buffer we are about to overwrite
#define READS_DONE() do {                                                     \
    asm volatile("s_waitcnt lgkmcnt(0)" ::: "memory");                        \
    __builtin_amdgcn_s_barrier();                                             \
    __builtin_amdgcn_sched_barrier(0);                                        \
} while (0)

#define NEXT_READY(N) do {                                                    \
    asm volatile("s_waitcnt vmcnt(" #N ")" ::: "memory");                     \
    __builtin_amdgcn_s_barrier();                                             \
} while (0)

    // prologue: B0, B1 DMA (order pinned), then A(0) to regs
    STAGE_B(H0, L0, 0);
    STAGE_B(H1, L1, 32);
    __builtin_amdgcn_sched_barrier(0);   // pin: B0,B1 issued before A
    PREF_A(aP, 0);
    NEXT_READY(6);                       // retire B0 (A(0)+B1 in flight)

    for (int s = 0; s < 22; s += 2) {
        // iter u=s (buf0, aP)
        LOADREGS_B(H0, L0);
        READS_DONE();
        STAGE_B(H0, L0, (s + 2) * 32);
        __builtin_amdgcn_sched_barrier(0);  // pin: B(u+2) before A(u+1)
        PREF_A(aN, (s + 1) * 32);
        DOMFMA(aP);                      // implicit wait on A(u) also retires B(u+1)
        NEXT_READY(6);                   // B(u+1) certainly retired; A(u+1)+B(u+2) in flight

        // iter u=s+1 (buf1, aN)
        LOADREGS_B(H1, L1);
        READS_DONE();
        STAGE_B(H1, L1, (s + 3) * 32);
        __builtin_amdgcn_sched_barrier(0);
        PREF_A(aP, (s + 2) * 32);
        DOMFMA(aN);
        NEXT_READY(6);
    }
    // iter 22 (buf0): no more B staging
    LOADREGS_B(H0, L0);
    READS_DONE();
    PREF_A(aN, 23 * 32);
    DOMFMA(aP);                          // retires B(23) (issued before A(22))
    NEXT_READY(4);                       // only A(23) may remain
    // iter 23 (buf1)
    LOADREGS_B(H1, L1);
    DOMFMA(aN);

#undef STAGE_B
#undef PREF_A
#undef LOADREGS_B
#undef DOMFMA
#undef READS_DONE
#undef NEXT_READY

    // LIF scan over t (registers only) + spike stores + suspect flags
    #pragma unroll
    for (int ni = 0; ni < 4; ni++)
        #pragma unroll
        for (int rr = 0; rr < 4; rr++) {
            int row = m0 + wave * 16 + quad * 4 + rr;
            int lc  = cb + ni * 16 + m16;
            float v = 0.f;
            bool suspect = false;
            #pragma unroll
            for (int t = 0; t < T_; t++) {
                v = v * 0.5f + acc[t][ni][rr];
                float d = v - 1.0f;
                if (fabsf(d) < SUSP_WIN) suspect = true;
                float sp = (d >= 0.f) ? 1.f : 0.f;
                v *= (1.f - sp);
                outp[(size_t)(t * M2_ + row) * Nloc + lc] = (bf16)sp;
            }
            if (suspect) {
                int ccol = n0 + ni * 16 + m16;
                unsigned idx = atomicAdd(susp, 1u);
                if (idx < SUSP_CAP) susp[1 + idx] = (unsigned)(row * 2048 + ccol);
            }
        }
}

// ---------------------------------------------------------------------------
// Kernel 2b: fp64 fixup of suspect trajectories. One wave per suspect.
// (r2-exact)
// ---------------------------------------------------------------------------
__global__ __launch_bounds__(256) void fixup_kernel(
    const bf16* __restrict__ xs, const float* __restrict__ q_w,
    const float* __restrict__ k_w, const float* __restrict__ v_w,
    bf16* __restrict__ q_sp, bf16* __restrict__ k_sp, bf16* __restrict__ v_sp,
    const unsigned* __restrict__ susp)
{
    unsigned count = susp[0];
    if (count > SUSP_CAP) count = SUSP_CAP;
    const int lane = threadIdx.x & 63;
    const int wid  = (blockIdx.x * blockDim.x + threadIdx.x) >> 6;
    const int nw   = (gridDim.x * blockDim.x) >> 6;
    for (unsigned i = wid; i < count; i += nw) {
        unsigned e = susp[1 + i];
        int row = e >> 11, col = e & 2047;
        const float* W; bf16* outp; int Nloc, lc;
        if (col < 768)      { W = q_w + (size_t)col * D_;         outp = q_sp; Nloc = 768; lc = col; }
        else if (col < 960) { W = k_w + (size_t)(col - 768) * D_; outp = k_sp; Nloc = 192; lc = col - 768; }
        else                { W = v_w + (size_t)(col - 960) * D_; outp = v_sp; Nloc = 192; lc = col - 960; }
        double v = 0.0;
        for (int t = 0; t < T_; ++t) {
            const bf16* ar = xs + (size_t)(t * M2_ + row) * D_;
            double y = 0.0;
            for (int k = lane; k < D_; k += 64)
                y += (double)(float)ar[k] * (double)W[k];
            #pragma unroll
            for (int off = 1; off < 64; off <<= 1)
                y += __shfl_xor(y, off);
            v = v * 0.5 + y;
            unsigned sp = (v >= 1.0) ? 1u : 0u;
            if (lane == 0) outp[(size_t)(t * M2_ + row) * Nloc + lc] = (bf16)(float)sp;
            if (sp) v = 0.0;
        }
    }
}

// ---------------------------------------------------------------------------
// Kernel 3: partial k^T v. Block (g, cc): c-range cc*64..+64 (8 slices ->
// 512 blocks, 2/CU). Vectorized bf16x8 global loads, scalar LDS transpose
// scatter. fp32 exact integer partials -> M_part[cc][g][96][96]. (r2-exact)
// ---------------------------------------------------------------------------
__global__ __launch_bounds__(256) void ktv_kernel(
    const bf16* __restrict__ k_sp, const bf16* __restrict__ v_sp,
    float* __restrict__ M_part)
{
    const int g    = blockIdx.x;
    const int cc   = blockIdx.y;
    const int kvh  = g % HL_;
    const int tb   = g / HL_;
    const int wave = threadIdx.x >> 6;
    const int lane = threadIdx.x & 63;
    const int m16  = lane & 15, quad = lane >> 4;

    __shared__ __align__(16) bf16 klds[96 * 40];
    __shared__ __align__(16) bf16 vlds[96 * 40];

    f32x4 acc[9];
    #pragma unroll
    for (int i = 0; i < 9; i++) { f32x4 z = {0.f,0.f,0.f,0.f}; acc[i] = z; }

    const bf16* kbase = k_sp + ((size_t)tb * C_ + cc * 64) * MKV_ + kvh * HD_;
    const bf16* vbase = v_sp + ((size_t)tb * C_ + cc * 64) * MKV_ + kvh * HD_;

    for (int c0 = 0; c0 < 64; c0 += 32) {
        __syncthreads();
        // 32c x 12segs x 2 arrays = 768 bf16x8 chunks, 3 per thread
        for (int ci = threadIdx.x; ci < 768; ci += 256) {
            int arr = ci & 1;
            int pos = ci >> 1;
            int c = pos / 12, seg = pos - c * 12;
            const bf16* src = (arr ? vbase : kbase) + (size_t)(c0 + c) * MKV_ + seg * 8;
            bf16x8 val = *(const bf16x8*)src;
            bf16* dst = arr ? vlds : klds;
            #pragma unroll
            for (int e = 0; e < 8; e++)
                dst[(seg * 8 + e) * 40 + c] = val[e];
        }
        __syncthreads();
        #pragma unroll
        for (int i = 0; i < 9; i++) {
            int tile = wave + i * 4;
            int mt = tile / 6, nt = tile % 6;
            bf16x8 a = *(const bf16x8*)(&klds[(mt * 16 + m16) * 40 + quad * 8]);
            bf16x8 b = *(const bf16x8*)(&vlds[(nt * 16 + m16) * 40 + quad * 8]);
            acc[i] = __builtin_amdgcn_mfma_f32_16x16x32_bf16(a, b, acc[i], 0, 0, 0);
        }
    }
    float* op = M_part + ((size_t)cc * 64 + g) * HD_ * HD_;
    #pragma unroll
    for (int i = 0; i < 9; i++) {
        int tile = wave + i * 4;
        int mt = tile / 6, nt = tile % 6;
        #pragma unroll
        for (int r = 0; r < 4; r++) {
            int d = mt * 16 + quad * 4 + r;
            int j = nt * 16 + m16;
            op[(size_t)j * HD_ + d] = acc[i][r];
        }
    }
}

// ---------------------------------------------------------------------------
// Kernel 3b: sum 8 partials, split to exact hi/lo bf16. (r2-exact)
// ---------------------------------------------------------------------------
__global__ __launch_bounds__(256) void cvtM_kernel(
    const float* __restrict__ M_part, bf16* __restrict__ M_hi,
    bf16* __restrict__ M_lo)
{
    int i = blockIdx.x * 256 + threadIdx.x;
    if (i >= 64 * HD_ * HD_) return;
    float m = 0.f;
    #pragma unroll
    for (int j = 0; j < 8; j++)
        m += M_part[i + (size_t)j * 589824];
    bf16 h = (bf16)m;
    M_hi[i] = h;
    M_lo[i] = (bf16)(m - (float)h);
}

// ---------------------------------------------------------------------------
// Kernel 4: out_attn = 0.1 * q @ M. Block (tbh, c128): M hi/lo staged once
// in padded LDS (row stride 104 elems -> conflict-free b128 reads). (r2-exact)
// ---------------------------------------------------------------------------
__global__ __launch_bounds__(256) void qm_kernel(
    const bf16* __restrict__ q_sp, const bf16* __restrict__ M_hi,
    const bf16* __restrict__ M_lo, bf16* __restrict__ out_attn)
{
    const int tbh  = blockIdx.x;
    const int h    = tbh % H_;
    const int tb   = tbh / H_;
    const int g    = tb * HL_ + (h >> 2);
    const int wave = threadIdx.x >> 6;
    const int lane = threadIdx.x & 63;
    const int m16  = lane & 15, quad = lane >> 4;
    const int cw   = blockIdx.y * 128 + wave * 32;

    __shared__ __align__(16) bf16 Mh[96 * 104];
    __shared__ __align__(16) bf16 Ml[96 * 104];
    {   // stage M: 96 rows x 12 segs = 1152 chunks per array
        const bf16* gh = M_hi + (size_t)g * HD_ * HD_;
        const bf16* gl = M_lo + (size_t)g * HD_ * HD_;
        #pragma unroll
        for (int j = 0; j < 5; j++) {
            int ci = j * 256 + threadIdx.x;
            if (ci < 1152) {
                int row = ci / 12, seg = ci % 12;
                *(bf16x8*)&Mh[row * 104 + seg * 8] = *(const bf16x8*)(gh + row * HD_ + seg * 8);
                *(bf16x8*)&Ml[row * 104 + seg * 8] = *(const bf16x8*)(gl + row * HD_ + seg * 8);
            }
        }
    }
    __syncthreads();

    f32x4 acc[2][6];
    #pragma unroll
    for (int mi = 0; mi < 2; mi++)
        #pragma unroll
        for (int nt = 0; nt < 6; nt++) { f32x4 z = {0.f,0.f,0.f,0.f}; acc[mi][nt] = z; }

    #pragma unroll
    for (int ks = 0; ks < 3; ++ks) {
        bf16x8 a[2];
        #pragma unroll
        for (int mi = 0; mi < 2; mi++)
            a[mi] = *(const bf16x8*)(q_sp + ((size_t)(tb * C_ + cw + mi * 16 + m16)) * D_
                                     + h * HD_ + ks * 32 + quad * 8);
        #pragma unroll
        for (int nt = 0; nt < 6; ++nt) {
            bf16x8 bh = *(const bf16x8*)&Mh[(nt * 16 + m16) * 104 + ks * 32 + quad * 8];
            bf16x8 bl = *(const bf16x8*)&Ml[(nt * 16 + m16) * 104 + ks * 32 + quad * 8];
            #pragma unroll
            for (int mi = 0; mi < 2; mi++) {
                acc[mi][nt] = __builtin_amdgcn_mfma_f32_16x16x32_bf16(a[mi], bh, acc[mi][nt], 0, 0, 0);
                acc[mi][nt] = __builtin_amdgcn_mfma_f32_16x16x32_bf16(a[mi], bl, acc[mi][nt], 0, 0, 0);
            }
        }
    }
    #pragma unroll
    for (int mi = 0; mi < 2; mi++)
        #pragma unroll
        for (int nt = 0; nt < 6; nt++)
            #pragma unroll
            for (int r = 0; r < 4; r++) {
                int c = cw + mi * 16 + quad * 4 + r;
                int j = nt * 16 + m16;
                out_attn[((size_t)(tb * C_ + c)) * D_ + h * HD_ + j] = (bf16)(0.1f * acc[mi][nt][r]);
            }
}

// ---------------------------------------------------------------------------
// Kernel 5: final = out_attn @ wo^T. 128x128 tile, BK=64, XOR-swizzled LDS.
// (r2-exact)
// ---------------------------------------------------------------------------
__global__ __launch_bounds__(256) void final_gemm_kernel(
    const bf16* __restrict__ A, const bf16* __restrict__ W, float* __restrict__ out)
{
    __shared__ __align__(16) bf16 Alds[128 * 64];   // 16 KB
    __shared__ __align__(16) bf16 Blds[128 * 64];   // 16 KB
    const int tid  = threadIdx.x;
    const int wave = tid >> 6, lane = tid & 63;
    const int m16  = lane & 15, quad = lane >> 4;
    const int wm   = wave >> 1, wn = wave & 1;
    const int m0   = blockIdx.x * 128, n0 = blockIdx.y * 128;

    f32x4 acc[4][4];
    #pragma unroll
    for (int a = 0; a < 4; a++)
        #pragma unroll
        for (int b = 0; b < 4; b++) { f32x4 z = {0.f,0.f,0.f,0.f}; acc[a][b] = z; }

    for (int k0 = 0; k0 < D_; k0 += 64) {
        __syncthreads();
        #pragma unroll
        for (int j = 0; j < 4; j++) {
            int ci = j * 256 + tid;
            int row = ci >> 3, slot = ci & 7;
            int seg = slot ^ ((row >> 1) & 7);
            gld16(A + (size_t)(m0 + row) * D_ + k0 + seg * 8, Alds + ci * 8);
            gld16(W + (size_t)(n0 + row) * D_ + k0 + seg * 8, Blds + ci * 8);
        }
        __syncthreads();
        #pragma unroll
        for (int kc = 0; kc < 2; kc++) {
            bf16x8 a[4], b[4];
            #pragma unroll
            for (int mi = 0; mi < 4; mi++) {
                int row = wm * 64 + mi * 16 + m16;
                a[mi] = *(const bf16x8*)&Alds[row * 64 + (((kc * 4 + quad) ^ ((row >> 1) & 7)) * 8)];
            }
            #pragma unroll
            for (int ni = 0; ni < 4; ni++) {
                int row = wn * 64 + ni * 16 + m16;
                b[ni] = *(const bf16x8*)&Blds[row * 64 + (((kc * 4 + quad) ^ ((row >> 1) & 7)) * 8)];
            }
            #pragma unroll
            for (int mi = 0; mi < 4; mi++)
                #pragma unroll
                for (int ni = 0; ni < 4; ni++)
                    acc[mi][ni] = __builtin_amdgcn_mfma_f32_16x16x32_bf16(a[mi], b[ni], acc[mi][ni], 0, 0, 0);
        }
    }
    #pragma unroll
    for (int mi = 0; mi < 4; mi++)
        #pragma unroll
        for (int ni = 0; ni < 4; ni++)
            #pragma unroll
            for (int r = 0; r < 4; r++) {
                int row = m0 + wm * 64 + mi * 16 + quad * 4 + r;
                int col = n0 + wn * 64 + ni * 16 + m16;
                out[(size_t)row * D_ + col] = acc[mi][ni][r];
            }
}

// ---------------------------------------------------------------------------
extern "C" void kernel_launch(void* const* d_in, const int* in_sizes, int n_in,
                              void* d_out, int out_size, void* d_ws, size_t ws_size,
                              hipStream_t stream) {
    const float* x    = (const float*)d_in[0];
    const float* q_w  = (const float*)d_in[1];
    const float* k_w  = (const float*)d_in[2];
    const float* v_w  = (const float*)d_in[3];
    const float* wo_w = (const float*)d_in[4];
    float* out = (float*)d_out;

    char* ws = (char*)d_ws;
    bf16* xs    = (bf16*)(ws);                  // 25,165,824  (T,M2,768)
    bf16* q_sp  = (bf16*)(ws + 25165824);       // 25,165,824  (T,M2,768)
    bf16* k_sp  = (bf16*)(ws + 50331648);       //  6,291,456  (T,M2,192)
    bf16* v_sp  = (bf16*)(ws + 56623104);       //  6,291,456  (T,M2,192)
    bf16* whi   = (bf16*)(ws + 62914560);       //  1,769,472  (1152,768)
    bf16* wlo   = (bf16*)(ws + 64684032);       //  1,769,472
    bf16* wo_bf = (bf16*)(ws + 66453504);       //  1,179,648
    bf16* M_hi  = (bf16*)(ws + 67633152);       //  1,179,648  (64,96,96)
    bf16* M_lo  = (bf16*)(ws + 68812800);       //  1,179,648
    unsigned* susp = (unsigned*)(ws + 69992448);//    262,148  (count + entries)
    bf16* out_attn = xs;                        // alias: xs dead after fixup
    float* M_part  = out;                       // d_out as scratch (18.9 MB of 50 MB)

    hipLaunchKernelGGL(prep_kernel, dim3(2048), dim3(256), 0, stream,
                       x, q_w, k_w, v_w, wo_w, xs, whi, wlo, wo_bf, susp);
    hipLaunchKernelGGL(proj_lif_kernel, dim3(M2_ / 64, NCOMB / 64), dim3(256), 0, stream,
                       xs, whi, wlo, q_sp, k_sp, v_sp, susp);
    hipLaunchKernelGGL(fixup_kernel, dim3(256), dim3(256), 0, stream,
                       xs, q_w, k_w, v_w, q_sp, k_sp, v_sp, susp);
    hipLaunchKernelGGL(ktv_kernel, dim3(T_ * B_ * HL_, 8), dim3(256), 0, stream,
                       k_sp, v_sp, M_part);
    hipLaunchKernelGGL(cvtM_kernel, dim3((64 * HD_ * HD_ + 255) / 256), dim3(256), 0, stream,
                       M_part, M_hi, M_lo);
    hipLaunchKernelGGL(qm_kernel, dim3(T_ * B_ * H_, C_ / 128), dim3(256), 0, stream,
                       q_sp, M_hi, M_lo, out_attn);
    hipLaunchKernelGGL(final_gemm_kernel, dim3(M3_ / 128, D_ / 128), dim3(256), 0, stream,
                       out_attn, wo_bf, out);
}

// Round 5
// 255.812 us; speedup vs baseline: 2.0287x; 1.0892x over previous
//
#include <hip/hip_runtime.h>

typedef __bf16 bf16;
typedef __bf16 bf16x4 __attribute__((ext_vector_type(4)));
typedef __bf16 bf16x8 __attribute__((ext_vector_type(8)));
typedef float f32x4 __attribute__((ext_vector_type(4)));

#define T_ 4
#define B_ 8
#define C_ 512
#define D_ 768
#define H_ 8
#define HL_ 2
#define HD_ 96
#define MKV_ 192
#define M2_ 4096            // B*C
#define BCD_ 3145728        // B*C*D
#define M3_ 16384           // T*B*C
#define NCOMB 1152          // q(768) + k(192) + v(192)
#define SUSP_WIN 2e-4f

// async global->LDS, 16B per lane (dest = wave-uniform base + lane*16; no pad)
__device__ __forceinline__ void gld16(const bf16* g, bf16* l) {
    __builtin_amdgcn_global_load_lds(
        (const __attribute__((address_space(1))) unsigned int*)g,
        (__attribute__((address_space(3))) unsigned int*)l, 16, 0, 0);
}

// all waves finished reading the LDS buffer we are about to overwrite
#define READS_DONE() do {                                                     \
    asm volatile("s_waitcnt lgkmcnt(0)" ::: "memory");                        \
    __builtin_amdgcn_s_barrier();                                             \
    __builtin_amdgcn_sched_barrier(0);                                        \
} while (0)

// counted wait: next buffer's loads (issued a full iter ago) have landed;
// the just-issued ones stay in flight
#define NEXT_READY(N) do {                                                    \
    asm volatile("s_waitcnt vmcnt(" #N ")" ::: "memory");                     \
    __builtin_amdgcn_s_barrier();                                             \
} while (0)

// ---------------------------------------------------------------------------
// Kernel 1: fused prep — VECTORIZED. xs=lif(x) fp64 scan (8 elems/thread,
// float4 loads + bf16x8 stores), q/k/v hi/lo split (float4 -> 2x bf16x4),
// wo bf16 cvt.
// ---------------------------------------------------------------------------
__global__ __launch_bounds__(256) void prep_kernel(
    const float* __restrict__ x, const float* __restrict__ q_w,
    const float* __restrict__ k_w, const float* __restrict__ v_w,
    const float* __restrict__ wo_w, bf16* __restrict__ xs,
    bf16* __restrict__ whi, bf16* __restrict__ wlo, bf16* __restrict__ wo_bf)
{
    const int t0 = blockIdx.x * 256 + threadIdx.x;
    const int stride = gridDim.x * 256;
    for (int i = t0 * 8; i < BCD_; i += stride * 8) {
        double v[8] = {0.0, 0.0, 0.0, 0.0, 0.0, 0.0, 0.0, 0.0};
        #pragma unroll
        for (int t = 0; t < T_; ++t) {
            const float* xp = x + (size_t)t * BCD_ + i;
            f32x4 xa = *(const f32x4*)xp;
            f32x4 xb = *(const f32x4*)(xp + 4);
            bf16x8 s;
            #pragma unroll
            for (int e = 0; e < 8; ++e) {
                float xe = (e < 4) ? xa[e] : xb[e - 4];
                v[e] = v[e] * 0.5 + (double)xe;
                float sp = (v[e] >= 1.0) ? 1.f : 0.f;
                s[e] = (bf16)sp;
                v[e] *= (double)(1.f - sp);     // exact: *0 or *1
            }
            *(bf16x8*)(xs + (size_t)t * BCD_ + i) = s;
        }
    }
    for (int i = t0 * 4; i < NCOMB * D_; i += stride * 4) {
        int row = i / D_, col = i - row * D_;
        const float* src;
        if (row < 768)      src = q_w + (size_t)row * D_ + col;
        else if (row < 960) src = k_w + (size_t)(row - 768) * D_ + col;
        else                src = v_w + (size_t)(row - 960) * D_ + col;
        f32x4 wv = *(const f32x4*)src;
        bf16x4 hh, ll;
        #pragma unroll
        for (int e = 0; e < 4; ++e) {
            bf16 h = (bf16)wv[e];
            hh[e] = h;
            ll[e] = (bf16)(wv[e] - (float)h);
        }
        *(bf16x4*)(whi + i) = hh;
        *(bf16x4*)(wlo + i) = ll;
    }
    for (int i = t0 * 4; i < D_ * D_; i += stride * 4) {
        f32x4 wv = *(const f32x4*)(wo_w + i);
        bf16x4 c;
        #pragma unroll
        for (int e = 0; e < 4; ++e) c[e] = (bf16)wv[e];
        *(bf16x4*)(wo_bf + i) = c;
    }
}

// ---------------------------------------------------------------------------
// Kernel 2: combined spiking projection (r2-exact schedule: BK=32, named
// dbuf LDS, counted-vmcnt full-iteration prefetch, 4-slot XOR swizzle,
// XCD-aware block swizzle) + IN-WAVE fp64 fixup: suspects are recomputed
// cooperatively by the owning wave via __ballot (replaces susp list +
// separate fixup kernel; removes the fixup->ktv ordering hazard).
// ---------------------------------------------------------------------------
__global__ __launch_bounds__(256, 3) void proj_lif_kernel(
    const bf16* __restrict__ xs, const bf16* __restrict__ Whi,
    const bf16* __restrict__ Wlo,
    const float* __restrict__ q_w, const float* __restrict__ k_w,
    const float* __restrict__ v_w,
    bf16* __restrict__ q_sp, bf16* __restrict__ k_sp, bf16* __restrict__ v_sp)
{
    __shared__ __align__(16) bf16 A0[T_][64 * 32];   // 16 KB
    __shared__ __align__(16) bf16 A1[T_][64 * 32];   // 16 KB
    __shared__ __align__(16) bf16 H0[64 * 32];       //  4 KB
    __shared__ __align__(16) bf16 H1[64 * 32];       //  4 KB
    __shared__ __align__(16) bf16 L0[64 * 32];       //  4 KB
    __shared__ __align__(16) bf16 L1[64 * 32];       //  4 KB  (48 KB total)

    const int tid  = threadIdx.x;
    const int wave = tid >> 6, lane = tid & 63;
    const int m16  = lane & 15, quad = lane >> 4;
    const int wm   = wave >> 1, wn = wave & 1;

    // bijective XCD swizzle: xcd = bid&7 gets m-tiles [xcd*8, xcd*8+8) x all n
    const int bid   = blockIdx.y * 64 + blockIdx.x;   // grid (64, 18)
    const int xcd   = bid & 7;
    const int local = bid >> 3;                        // 0..143
    const int m0    = ((xcd << 3) | (local & 7)) * 64; // over M2
    const int n0    = (local >> 3) * 64;               // over NCOMB

    // output section for this wave's 32 columns
    const int colb = n0 + wn * 32;
    bf16* outp; int Nloc, cb;
    if (colb < 768)      { outp = q_sp; Nloc = 768; cb = colb; }
    else if (colb < 960) { outp = k_sp; Nloc = 192; cb = colb - 768; }
    else                 { outp = v_sp; Nloc = 192; cb = colb - 960; }

    f32x4 acc[T_][2][2];
    #pragma unroll
    for (int t = 0; t < T_; t++)
        #pragma unroll
        for (int a = 0; a < 2; a++)
            #pragma unroll
            for (int b = 0; b < 2; b++) { f32x4 z = {0.f,0.f,0.f,0.f}; acc[t][a][b] = z; }

    // staging geometry: chunk = tid -> row = tid>>2, slot = tid&3,
    // source seg = slot ^ ((row>>1)&3)  (inverse swizzle on global src)
    const int srow = tid >> 2;
    const int sseg = (tid & 3) ^ ((tid >> 3) & 3);

#define STAGE(Ab, Hb, Lb, k0) do {                                            \
    _Pragma("unroll")                                                         \
    for (int t = 0; t < T_; t++)                                              \
        gld16(xs + (size_t)(t * M2_ + m0 + srow) * D_ + (k0) + sseg * 8,      \
              &Ab[t][tid * 8]);                                               \
    gld16(Whi + (size_t)(n0 + srow) * D_ + (k0) + sseg * 8, &Hb[tid * 8]);    \
    gld16(Wlo + (size_t)(n0 + srow) * D_ + (k0) + sseg * 8, &Lb[tid * 8]);    \
} while (0)

    bf16x8 a[T_][2], bh[2], bl[2];

#define LOADREGS(Ab, Hb, Lb) do {                                             \
    _Pragma("unroll")                                                         \
    for (int mi = 0; mi < 2; mi++) {                                          \
        int row = wm * 32 + mi * 16 + m16;                                    \
        int off = row * 32 + ((quad ^ ((row >> 1) & 3)) * 8);                 \
        _Pragma("unroll")                                                     \
        for (int t = 0; t < T_; t++) a[t][mi] = *(const bf16x8*)&Ab[t][off];  \
    }                                                                         \
    _Pragma("unroll")                                                         \
    for (int ni = 0; ni < 2; ni++) {                                          \
        int row = wn * 32 + ni * 16 + m16;                                    \
        int off = row * 32 + ((quad ^ ((row >> 1) & 3)) * 8);                 \
        bh[ni] = *(const bf16x8*)&Hb[off];                                    \
        bl[ni] = *(const bf16x8*)&Lb[off];                                    \
    }                                                                         \
} while (0)

#define DOMFMA() do {                                                         \
    __builtin_amdgcn_s_setprio(1);                                            \
    _Pragma("unroll")                                                         \
    for (int ni = 0; ni < 2; ni++)                                            \
        _Pragma("unroll")                                                     \
        for (int t = 0; t < T_; t++)                                          \
            _Pragma("unroll")                                                 \
            for (int mi = 0; mi < 2; mi++) {                                  \
                acc[t][mi][ni] = __builtin_amdgcn_mfma_f32_16x16x32_bf16(     \
                    a[t][mi], bh[ni], acc[t][mi][ni], 0, 0, 0);               \
                acc[t][mi][ni] = __builtin_amdgcn_mfma_f32_16x16x32_bf16(     \
                    a[t][mi], bl[ni], acc[t][mi][ni], 0, 0, 0);               \
            }                                                                 \
    __builtin_amdgcn_s_setprio(0);                                            \
} while (0)

    STAGE(A0, H0, L0, 0);
    STAGE(A1, H1, L1, 32);
    NEXT_READY(6);                       // buf0 ready, buf1 in flight

    for (int s = 0; s < 22; s += 2) {    // iters u = s (buf0), u = s+1 (buf1)
        LOADREGS(A0, H0, L0);
        READS_DONE();
        STAGE(A0, H0, L0, (s + 2) * 32);
        DOMFMA();
        NEXT_READY(6);                   // buf1 (tile s+1) ready

        LOADREGS(A1, H1, L1);
        READS_DONE();
        STAGE(A1, H1, L1, (s + 3) * 32);
        DOMFMA();
        NEXT_READY(6);                   // buf0 (tile s+2) ready
    }
    // iter 22 (buf0): no more staging
    LOADREGS(A0, H0, L0);
    READS_DONE();
    DOMFMA();
    NEXT_READY(0);                       // buf1 (tile 23) ready
    // iter 23 (buf1)
    LOADREGS(A1, H1, L1);
    DOMFMA();

#undef STAGE
#undef LOADREGS
#undef DOMFMA

    // LIF scan over t (registers only) + spike stores + suspect bitmask
    unsigned susmask = 0;
    #pragma unroll
    for (int mi = 0; mi < 2; mi++)
        #pragma unroll
        for (int ni = 0; ni < 2; ni++)
            #pragma unroll
            for (int rr = 0; rr < 4; rr++) {
                int row = m0 + wm * 32 + mi * 16 + quad * 4 + rr;
                int lc  = cb + ni * 16 + m16;
                float v = 0.f;
                bool suspect = false;
                #pragma unroll
                for (int t = 0; t < T_; t++) {
                    v = v * 0.5f + acc[t][mi][ni][rr];
                    float d = v - 1.0f;
                    if (fabsf(d) < SUSP_WIN) suspect = true;
                    float sp = (d >= 0.f) ? 1.f : 0.f;
                    v *= (1.f - sp);
                    outp[(size_t)(t * M2_ + row) * Nloc + lc] = (bf16)sp;
                }
                if (suspect) susmask |= 1u << (mi * 8 + ni * 4 + rr);
            }

    // wave-cooperative fp64 fixup of suspects (each suspect owned by this wave)
    #pragma unroll 1
    for (int b = 0; b < 16; ++b) {
        unsigned long long mask = __ballot((susmask >> b) & 1u);
        while (mask) {
            int src = (int)__ffsll((long long)mask) - 1;   // wave-uniform
            mask &= mask - 1;
            int mi = b >> 3, ni = (b >> 2) & 1, rr = b & 3;
            int grow = m0 + wm * 32 + mi * 16 + ((src >> 4) << 2) + rr;
            int gc   = n0 + wn * 32 + ni * 16 + (src & 15);
            const float* Wr;
            if (gc < 768)      Wr = q_w + (size_t)gc * D_;
            else if (gc < 960) Wr = k_w + (size_t)(gc - 768) * D_;
            else               Wr = v_w + (size_t)(gc - 960) * D_;
            int lc = cb + ni * 16 + (src & 15);
            double v = 0.0;
            for (int t = 0; t < T_; ++t) {
                const bf16* ar = xs + (size_t)(t * M2_ + grow) * D_;
                double y = 0.0;
                for (int k = lane; k < D_; k += 64)
                    y += (double)(float)ar[k] * (double)Wr[k];
                #pragma unroll
                for (int off = 1; off < 64; off <<= 1)
                    y += __shfl_xor(y, off);
                v = v * 0.5 + y;
                float sp = (v >= 1.0) ? 1.f : 0.f;
                if (lane == 0)
                    outp[(size_t)(t * M2_ + grow) * Nloc + lc] = (bf16)sp;
                if (sp != 0.f) v = 0.0;
            }
        }
    }
}

// ---------------------------------------------------------------------------
// Kernel 3: partial k^T v. Block (g, cc): c-range cc*64..+64 (8 slices ->
// 512 blocks, 2/CU). Vectorized bf16x8 global loads, scalar LDS transpose
// scatter. fp32 exact integer partials -> M_part[cc][g][96][96]. (r2-exact)
// ---------------------------------------------------------------------------
__global__ __launch_bounds__(256) void ktv_kernel(
    const bf16* __restrict__ k_sp, const bf16* __restrict__ v_sp,
    float* __restrict__ M_part)
{
    const int g    = blockIdx.x;
    const int cc   = blockIdx.y;
    const int kvh  = g % HL_;
    const int tb   = g / HL_;
    const int wave = threadIdx.x >> 6;
    const int lane = threadIdx.x & 63;
    const int m16  = lane & 15, quad = lane >> 4;

    __shared__ __align__(16) bf16 klds[96 * 40];
    __shared__ __align__(16) bf16 vlds[96 * 40];

    f32x4 acc[9];
    #pragma unroll
    for (int i = 0; i < 9; i++) { f32x4 z = {0.f,0.f,0.f,0.f}; acc[i] = z; }

    const bf16* kbase = k_sp + ((size_t)tb * C_ + cc * 64) * MKV_ + kvh * HD_;
    const bf16* vbase = v_sp + ((size_t)tb * C_ + cc * 64) * MKV_ + kvh * HD_;

    for (int c0 = 0; c0 < 64; c0 += 32) {
        __syncthreads();
        // 32c x 12segs x 2 arrays = 768 bf16x8 chunks, 3 per thread
        for (int ci = threadIdx.x; ci < 768; ci += 256) {
            int arr = ci & 1;
            int pos = ci >> 1;
            int c = pos / 12, seg = pos - c * 12;
            const bf16* src = (arr ? vbase : kbase) + (size_t)(c0 + c) * MKV_ + seg * 8;
            bf16x8 val = *(const bf16x8*)src;
            bf16* dst = arr ? vlds : klds;
            #pragma unroll
            for (int e = 0; e < 8; e++)
                dst[(seg * 8 + e) * 40 + c] = val[e];
        }
        __syncthreads();
        #pragma unroll
        for (int i = 0; i < 9; i++) {
            int tile = wave + i * 4;
            int mt = tile / 6, nt = tile % 6;
            bf16x8 a = *(const bf16x8*)(&klds[(mt * 16 + m16) * 40 + quad * 8]);
            bf16x8 b = *(const bf16x8*)(&vlds[(nt * 16 + m16) * 40 + quad * 8]);
            acc[i] = __builtin_amdgcn_mfma_f32_16x16x32_bf16(a, b, acc[i], 0, 0, 0);
        }
    }
    float* op = M_part + ((size_t)cc * 64 + g) * HD_ * HD_;
    #pragma unroll
    for (int i = 0; i < 9; i++) {
        int tile = wave + i * 4;
        int mt = tile / 6, nt = tile % 6;
        #pragma unroll
        for (int r = 0; r < 4; r++) {
            int d = mt * 16 + quad * 4 + r;
            int j = nt * 16 + m16;
            op[(size_t)j * HD_ + d] = acc[i][r];
        }
    }
}

// ---------------------------------------------------------------------------
// Kernel 3b: sum 8 partials, split to exact hi/lo bf16. (r2-exact)
// ---------------------------------------------------------------------------
__global__ __launch_bounds__(256) void cvtM_kernel(
    const float* __restrict__ M_part, bf16* __restrict__ M_hi,
    bf16* __restrict__ M_lo)
{
    int i = blockIdx.x * 256 + threadIdx.x;
    if (i >= 64 * HD_ * HD_) return;
    float m = 0.f;
    #pragma unroll
    for (int j = 0; j < 8; j++)
        m += M_part[i + (size_t)j * 589824];
    bf16 h = (bf16)m;
    M_hi[i] = h;
    M_lo[i] = (bf16)(m - (float)h);
}

// ---------------------------------------------------------------------------
// Kernel 4: out_attn = 0.1 * q @ M. Block (tbh, c128): M hi/lo staged once
// in padded LDS (row stride 104 elems -> conflict-free b128 reads). (r2-exact)
// ---------------------------------------------------------------------------
__global__ __launch_bounds__(256) void qm_kernel(
    const bf16* __restrict__ q_sp, const bf16* __restrict__ M_hi,
    const bf16* __restrict__ M_lo, bf16* __restrict__ out_attn)
{
    const int tbh  = blockIdx.x;
    const int h    = tbh % H_;
    const int tb   = tbh / H_;
    const int g    = tb * HL_ + (h >> 2);
    const int wave = threadIdx.x >> 6;
    const int lane = threadIdx.x & 63;
    const int m16  = lane & 15, quad = lane >> 4;
    const int cw   = blockIdx.y * 128 + wave * 32;

    __shared__ __align__(16) bf16 Mh[96 * 104];
    __shared__ __align__(16) bf16 Ml[96 * 104];
    {   // stage M: 96 rows x 12 segs = 1152 chunks per array
        const bf16* gh = M_hi + (size_t)g * HD_ * HD_;
        const bf16* gl = M_lo + (size_t)g * HD_ * HD_;
        #pragma unroll
        for (int j = 0; j < 5; j++) {
            int ci = j * 256 + threadIdx.x;
            if (ci < 1152) {
                int row = ci / 12, seg = ci % 12;
                *(bf16x8*)&Mh[row * 104 + seg * 8] = *(const bf16x8*)(gh + row * HD_ + seg * 8);
                *(bf16x8*)&Ml[row * 104 + seg * 8] = *(const bf16x8*)(gl + row * HD_ + seg * 8);
            }
        }
    }
    __syncthreads();

    f32x4 acc[2][6];
    #pragma unroll
    for (int mi = 0; mi < 2; mi++)
        #pragma unroll
        for (int nt = 0; nt < 6; nt++) { f32x4 z = {0.f,0.f,0.f,0.f}; acc[mi][nt] = z; }

    #pragma unroll
    for (int ks = 0; ks < 3; ++ks) {
        bf16x8 a[2];
        #pragma unroll
        for (int mi = 0; mi < 2; mi++)
            a[mi] = *(const bf16x8*)(q_sp + ((size_t)(tb * C_ + cw + mi * 16 + m16)) * D_
                                     + h * HD_ + ks * 32 + quad * 8);
        #pragma unroll
        for (int nt = 0; nt < 6; ++nt) {
            bf16x8 bh = *(const bf16x8*)&Mh[(nt * 16 + m16) * 104 + ks * 32 + quad * 8];
            bf16x8 bl = *(const bf16x8*)&Ml[(nt * 16 + m16) * 104 + ks * 32 + quad * 8];
            #pragma unroll
            for (int mi = 0; mi < 2; mi++) {
                acc[mi][nt] = __builtin_amdgcn_mfma_f32_16x16x32_bf16(a[mi], bh, acc[mi][nt], 0, 0, 0);
                acc[mi][nt] = __builtin_amdgcn_mfma_f32_16x16x32_bf16(a[mi], bl, acc[mi][nt], 0, 0, 0);
            }
        }
    }
    #pragma unroll
    for (int mi = 0; mi < 2; mi++)
        #pragma unroll
        for (int nt = 0; nt < 6; nt++)
            #pragma unroll
            for (int r = 0; r < 4; r++) {
                int c = cw + mi * 16 + quad * 4 + r;
                int j = nt * 16 + m16;
                out_attn[((size_t)(tb * C_ + c)) * D_ + h * HD_ + j] = (bf16)(0.1f * acc[mi][nt][r]);
            }
}

// ---------------------------------------------------------------------------
// Kernel 5: final = out_attn @ wo^T. 128x128 tile, NOW r2-style pipeline:
// BK=32, named dbuf LDS (32 KB), counted-vmcnt full-iteration prefetch,
// 4-slot XOR swizzle. 16 MFMA + 8 ds_read + 4 gld16 per wave per K-step.
// ---------------------------------------------------------------------------
__global__ __launch_bounds__(256, 3) void final_gemm_kernel(
    const bf16* __restrict__ A, const bf16* __restrict__ W, float* __restrict__ out)
{
    __shared__ __align__(16) bf16 FA0[128 * 32];   // 8 KB
    __shared__ __align__(16) bf16 FA1[128 * 32];   // 8 KB
    __shared__ __align__(16) bf16 FB0[128 * 32];   // 8 KB
    __shared__ __align__(16) bf16 FB1[128 * 32];   // 8 KB  (32 KB total)

    const int tid  = threadIdx.x;
    const int wave = tid >> 6, lane = tid & 63;
    const int m16  = lane & 15, quad = lane >> 4;
    const int wm   = wave >> 1, wn = wave & 1;
    const int m0   = blockIdx.x * 128, n0 = blockIdx.y * 128;

    f32x4 acc[4][4];
    #pragma unroll
    for (int p = 0; p < 4; p++)
        #pragma unroll
        for (int q = 0; q < 4; q++) { f32x4 z = {0.f,0.f,0.f,0.f}; acc[p][q] = z; }

    // staging: 512 chunks/array, 2 per thread. row = ci>>2, slot = ci&3,
    // seg = slot ^ ((row>>1)&3)
    const int c0_ = tid,        r0_ = c0_ >> 2, g0_ = (c0_ & 3) ^ ((c0_ >> 3) & 3);
    const int c1_ = 256 + tid,  r1_ = c1_ >> 2, g1_ = (c1_ & 3) ^ ((c1_ >> 3) & 3);

#define FSTG(Ab, Bb, k0) do {                                                 \
    gld16(A + (size_t)(m0 + r0_) * D_ + (k0) + g0_ * 8, &Ab[c0_ * 8]);        \
    gld16(A + (size_t)(m0 + r1_) * D_ + (k0) + g1_ * 8, &Ab[c1_ * 8]);        \
    gld16(W + (size_t)(n0 + r0_) * D_ + (k0) + g0_ * 8, &Bb[c0_ * 8]);        \
    gld16(W + (size_t)(n0 + r1_) * D_ + (k0) + g1_ * 8, &Bb[c1_ * 8]);        \
} while (0)

    bf16x8 fa[4], fb[4];

#define FLOAD(Ab, Bb) do {                                                    \
    _Pragma("unroll")                                                         \
    for (int mi = 0; mi < 4; mi++) {                                          \
        int row = wm * 64 + mi * 16 + m16;                                    \
        int off = row * 32 + ((quad ^ ((row >> 1) & 3)) * 8);                 \
        fa[mi] = *(const bf16x8*)&Ab[off];                                    \
    }                                                                         \
    _Pragma("unroll")                                                         \
    for (int ni = 0; ni < 4; ni++) {                                          \
        int row = wn * 64 + ni * 16 + m16;                                    \
        int off = row * 32 + ((quad ^ ((row >> 1) & 3)) * 8);                 \
        fb[ni] = *(const bf16x8*)&Bb[off];                                    \
    }                                                                         \
} while (0)

#define FMFMA() do {                                                          \
    __builtin_amdgcn_s_setprio(1);                                            \
    _Pragma("unroll")                                                         \
    for (int mi = 0; mi < 4; mi++)                                            \
        _Pragma("unroll")                                                     \
        for (int ni = 0; ni < 4; ni++)                                        \
            acc[mi][ni] = __builtin_amdgcn_mfma_f32_16x16x32_bf16(            \
                fa[mi], fb[ni], acc[mi][ni], 0, 0, 0);                        \
    __builtin_amdgcn_s_setprio(0);                                            \
} while (0)

    FSTG(FA0, FB0, 0);
    FSTG(FA1, FB1, 32);
    NEXT_READY(4);                       // buf0 ready, buf1 in flight

    for (int s = 0; s < 22; s += 2) {    // 24 K-steps total
        FLOAD(FA0, FB0);
        READS_DONE();
        FSTG(FA0, FB0, (s + 2) * 32);
        FMFMA();
        NEXT_READY(4);

        FLOAD(FA1, FB1);
        READS_DONE();
        FSTG(FA1, FB1, (s + 3) * 32);
        FMFMA();
        NEXT_READY(4);
    }
    FLOAD(FA0, FB0);
    READS_DONE();
    FMFMA();
    NEXT_READY(0);
    FLOAD(FA1, FB1);
    FMFMA();

#undef FSTG
#undef FLOAD
#undef FMFMA

    #pragma unroll
    for (int mi = 0; mi < 4; mi++)
        #pragma unroll
        for (int ni = 0; ni < 4; ni++)
            #pragma unroll
            for (int r = 0; r < 4; r++) {
                int row = m0 + wm * 64 + mi * 16 + quad * 4 + r;
                int col = n0 + wn * 64 + ni * 16 + m16;
                out[(size_t)row * D_ + col] = acc[mi][ni][r];
            }
}

// ---------------------------------------------------------------------------
extern "C" void kernel_launch(void* const* d_in, const int* in_sizes, int n_in,
                              void* d_out, int out_size, void* d_ws, size_t ws_size,
                              hipStream_t stream) {
    const float* x    = (const float*)d_in[0];
    const float* q_w  = (const float*)d_in[1];
    const float* k_w  = (const float*)d_in[2];
    const float* v_w  = (const float*)d_in[3];
    const float* wo_w = (const float*)d_in[4];
    float* out = (float*)d_out;

    char* ws = (char*)d_ws;
    bf16* xs    = (bf16*)(ws);                  // 25,165,824  (T,M2,768)
    bf16* q_sp  = (bf16*)(ws + 25165824);       // 25,165,824  (T,M2,768)
    bf16* k_sp  = (bf16*)(ws + 50331648);       //  6,291,456  (T,M2,192)
    bf16* v_sp  = (bf16*)(ws + 56623104);       //  6,291,456  (T,M2,192)
    bf16* whi   = (bf16*)(ws + 62914560);       //  1,769,472  (1152,768)
    bf16* wlo   = (bf16*)(ws + 64684032);       //  1,769,472
    bf16* wo_bf = (bf16*)(ws + 66453504);       //  1,179,648
    bf16* M_hi  = (bf16*)(ws + 67633152);       //  1,179,648  (64,96,96)
    bf16* M_lo  = (bf16*)(ws + 68812800);       //  1,179,648
    bf16* out_attn = xs;                        // alias: xs dead after proj
    float* M_part  = out;                       // d_out as scratch (18.9 MB of 50 MB)

    hipLaunchKernelGGL(prep_kernel, dim3(1536), dim3(256), 0, stream,
                       x, q_w, k_w, v_w, wo_w, xs, whi, wlo, wo_bf);
    hipLaunchKernelGGL(proj_lif_kernel, dim3(M2_ / 64, NCOMB / 64), dim3(256), 0, stream,
                       xs, whi, wlo, q_w, k_w, v_w, q_sp, k_sp, v_sp);
    hipLaunchKernelGGL(ktv_kernel, dim3(T_ * B_ * HL_, 8), dim3(256), 0, stream,
                       k_sp, v_sp, M_part);
    hipLaunchKernelGGL(cvtM_kernel, dim3((64 * HD_ * HD_ + 255) / 256), dim3(256), 0, stream,
                       M_part, M_hi, M_lo);
    hipLaunchKernelGGL(qm_kernel, dim3(T_ * B_ * H_, C_ / 128), dim3(256), 0, stream,
                       q_sp, M_hi, M_lo, out_attn);
    hipLaunchKernelGGL(final_gemm_kernel, dim3(M3_ / 128, D_ / 128), dim3(256), 0, stream,
                       out_attn, wo_bf, out);
}